// Round 1
// 1105.717 us; speedup vs baseline: 1.1695x; 1.1695x over previous
//
#include <hip/hip_runtime.h>
#include <cstdint>
#include <cstddef>

#define HD    1024
#define SLOTS 272
#define MEMS  256
#define BATCH 8
#define TT    4096
#define RR    (BATCH*TT)
#define RANKC 10

#define GAMMA 0.92f
#define BETA  0.08f
#define PTS   0.4f

// packed fp32 (v_pk_fma_f32 / v_pk_mul_f32 on gfx950): halves VALU issue count
// in the issue-cadence-bound single-wave scan.
typedef float f32x2 __attribute__((ext_vector_type(2)));
#define PKFMA(a, b, c) __builtin_elementwise_fma((a), (b), (c))

// ---------------------------------------------------------------------------
// DPP wave64 sum-allreduce: 6 VALU-speed cross-lane adds + readlane broadcast.
// ---------------------------------------------------------------------------
#define DPP_ADD(v, ctrl, rmask)                                                   \
    v += __int_as_float(__builtin_amdgcn_update_dpp(                              \
        0, __float_as_int(v), (ctrl), (rmask), 0xf, true))

__device__ __forceinline__ float wave_sum_bcast(float v)
{
    DPP_ADD(v, 0xB1,  0xf);   // quad_perm [1,0,3,2]  : + lane^1
    DPP_ADD(v, 0x4E,  0xf);   // quad_perm [2,3,0,1]  : + lane^2
    DPP_ADD(v, 0x141, 0xf);   // row_half_mirror      : + other quad
    DPP_ADD(v, 0x140, 0xf);   // row_mirror           : + other 8-group
    DPP_ADD(v, 0x142, 0xa);   // row_bcast15 -> rows 1,3
    DPP_ADD(v, 0x143, 0xc);   // row_bcast31 -> rows 2,3 (lane 63 = total)
    return __int_as_float(__builtin_amdgcn_readlane(__float_as_int(v), 63));
}

// ---------------------------------------------------------------------------
// prep: per-slot constants.
// consts (floats): [0]=wr[256] [256]=bg[256] [512]=A[256] [768]=B[256]
// [1024]=v0re[256] [1280]=v0im[256] [1536]=cos[256] [1792]=sin[256] [2048]=eta
//   c1 = gamma + eta*eps_diag, c2 = PTS*pred_diag, A = c1*cos - c2*sin,
//   B = c1*sin + c2*cos.  flags: [0]=eps_scale any nz, [1]=pred_scale any nz.
// ---------------------------------------------------------------------------
__global__ void prep_kernel(const float* __restrict__ t0re, const float* __restrict__ t0im,
                            const float* __restrict__ eta_raw,
                            const float* __restrict__ trot, const float* __restrict__ w_r,
                            const float* __restrict__ bgate,
                            const float* __restrict__ eps_scale, const float* __restrict__ pred_scale,
                            const float* __restrict__ eps_diag, const float* __restrict__ pred_diag,
                            float* __restrict__ consts, int* __restrict__ flags)
{
    __shared__ float red[MEMS];
    const int s = threadIdx.x;  // 256 threads
    const float tr = t0re[s], ti = t0im[s];
    red[s] = tr * tr + ti * ti;
    __syncthreads();
    for (int off = 128; off > 0; off >>= 1) {
        if (s < off) red[s] += red[s + off];
        __syncthreads();
    }
    const float nrm = sqrtf(fmaxf(red[0], 1e-16f));
    const float eta = log1pf(expf(eta_raw[0]));
    const float rc = cosf(trot[s]), rs = sinf(trot[s]);
    const float c1 = GAMMA + eta * eps_diag[s];
    const float c2 = PTS * pred_diag[s];
    consts[0 * MEMS + s] = 1.0f / (1.0f + expf(-w_r[s]));
    consts[1 * MEMS + s] = 1.0f / (1.0f + expf(-bgate[s]));
    consts[2 * MEMS + s] = c1 * rc - c2 * rs;   // A
    consts[3 * MEMS + s] = c1 * rs + c2 * rc;   // B
    consts[4 * MEMS + s] = tr / nrm;
    consts[5 * MEMS + s] = ti / nrm;
    consts[6 * MEMS + s] = rc;
    consts[7 * MEMS + s] = rs;
    if (s == 0) {
        consts[8 * MEMS] = eta;
        int f1 = 0, f2 = 0;
        for (int k = 0; k < RANKC; ++k) {
            if (eps_scale[k]  != 0.0f) f1 = 1;
            if (pred_scale[k] != 0.0f) f2 = 1;
        }
        flags[0] = f1;
        flags[1] = f2;
    }
}

// ---------------------------------------------------------------------------
// proj: M(R x 256) = X(R x 1024) * Q,  Q[k][n] = basis[k*272 + n]
// ---------------------------------------------------------------------------
__global__ __launch_bounds__(256) void proj_kernel(const float* __restrict__ x,
                                                   const float* __restrict__ basis,
                                                   float* __restrict__ M)
{
    __shared__ float As[32][68];  // [k][m], padded
    __shared__ float Bs[32][68];  // [k][n], padded
    const int tid  = threadIdx.x;
    const int row0 = blockIdx.x * 64;
    const int col0 = blockIdx.y * 64;
    const int mt = tid >> 4, nt = tid & 15;
    float acc[4][4] = {};
    for (int k0 = 0; k0 < HD; k0 += 32) {
        {
            int q = tid, m = q >> 3, kq = q & 7;
            float4 a = *(const float4*)&x[(size_t)(row0 + m) * HD + k0 + kq * 4];
            As[kq * 4 + 0][m] = a.x; As[kq * 4 + 1][m] = a.y;
            As[kq * 4 + 2][m] = a.z; As[kq * 4 + 3][m] = a.w;
            q = tid + 256; m = q >> 3; kq = q & 7;
            float4 b = *(const float4*)&x[(size_t)(row0 + m) * HD + k0 + kq * 4];
            As[kq * 4 + 0][m] = b.x; As[kq * 4 + 1][m] = b.y;
            As[kq * 4 + 2][m] = b.z; As[kq * 4 + 3][m] = b.w;
            q = tid; int k = q >> 4; int nq = q & 15;
            float4 c = *(const float4*)&basis[(size_t)(k0 + k) * SLOTS + col0 + nq * 4];
            *(float4*)&Bs[k][nq * 4] = c;
            q = tid + 256; k = q >> 4; nq = q & 15;
            float4 d = *(const float4*)&basis[(size_t)(k0 + k) * SLOTS + col0 + nq * 4];
            *(float4*)&Bs[k][nq * 4] = d;
        }
        __syncthreads();
#pragma unroll
        for (int kk = 0; kk < 32; ++kk) {
            float4 a = *(const float4*)&As[kk][mt * 4];
            float4 b = *(const float4*)&Bs[kk][nt * 4];
            float av[4] = {a.x, a.y, a.z, a.w};
            float bv[4] = {b.x, b.y, b.z, b.w};
#pragma unroll
            for (int i = 0; i < 4; ++i)
#pragma unroll
                for (int j = 0; j < 4; ++j) acc[i][j] += av[i] * bv[j];
        }
        __syncthreads();
    }
#pragma unroll
    for (int i = 0; i < 4; ++i) {
        float4 o = {acc[i][0], acc[i][1], acc[i][2], acc[i][3]};
        *(float4*)&M[(size_t)(row0 + mt * 4 + i) * MEMS + col0 + nt * 4] = o;
    }
}

// ---------------------------------------------------------------------------
// topk: per (b,t) row, find 8th-largest |m| (dup-counting), then mask the row
// IN PLACE: M[r,s] <- (|m|>=kth) ? BETA*m : 0.  Scan consumes it directly.
// ---------------------------------------------------------------------------
__global__ __launch_bounds__(64) void topk_kernel(float* __restrict__ M)
{
    const int r    = blockIdx.x;
    const int lane = threadIdx.x;
    float4 v = *(const float4*)&M[(size_t)r * MEMS + lane * 4];
    float vals[4] = {fabsf(v.x), fabsf(v.y), fabsf(v.z), fabsf(v.w)};
    float keep[4] = {vals[0], vals[1], vals[2], vals[3]};
    float kv = 0.0f;
#pragma unroll
    for (int it = 0; it < 8; ++it) {
        float lm = vals[0]; int li = 0;
#pragma unroll
        for (int j = 1; j < 4; ++j)
            if (vals[j] > lm) { lm = vals[j]; li = j; }
        float bm = lm; int bi = lane * 4 + li;
#pragma unroll
        for (int off = 1; off < 64; off <<= 1) {
            float om = __shfl_xor(bm, off);
            int   oi = __shfl_xor(bi, off);
            if (om > bm || (om == bm && oi < bi)) { bm = om; bi = oi; }
        }
        kv = bm;
        if ((bi >> 2) == lane) vals[bi & 3] = -1.0f;
    }
    float4 o;
    o.x = (keep[0] >= kv) ? BETA * v.x : 0.0f;
    o.y = (keep[1] >= kv) ? BETA * v.y : 0.0f;
    o.z = (keep[2] >= kv) ? BETA * v.z : 0.0f;
    o.w = (keep[3] >= kv) ? BETA * v.w : 0.0f;
    *(float4*)&M[(size_t)r * MEMS + lane * 4] = o;
}

// ---------------------------------------------------------------------------
// scan: one wave per batch, 4 slots/lane, all state in registers.
// M is pre-masked (= BETA*inj).
// Normalized-state form: carry v = u/||u|| and q = v_{t-1}.  Then
//   u1 = A o v_r - B o v_i + wr o q + m        (complex; m real)
//   inv = rsqrt(||u1||^2);  v' = u1*inv;  q' = v.
// All elementwise math in packed fp32 (f32x2 -> v_pk_fma_f32): the scan is a
// single-wave issue-cadence-bound serial chain, so halving instruction count
// halves step time.  Wout rows store the NORMALIZED real part directly (the
// normalize multiply happens anyway for the state), eliminating the invb side
// channel and its per-step lane0 exec-mask dance.
// Depth-16 prefetch ring; prefetch may read <=16 rows past the slice (valid
// adjacent ws/d_out memory, values unused).
// ---------------------------------------------------------------------------
__global__ __launch_bounds__(64) void scan_kernel(const float* __restrict__ M,
                                                  const float* __restrict__ consts,
                                                  const int* __restrict__ flags,
                                                  const float* __restrict__ eps_fac,
                                                  const float* __restrict__ eps_scale,
                                                  const float* __restrict__ eps_diag,
                                                  const float* __restrict__ pred_fac,
                                                  const float* __restrict__ pred_scale,
                                                  const float* __restrict__ pred_diag,
                                                  float* __restrict__ Wout)
{
    const int b    = blockIdx.x;
    const int lane = threadIdx.x;
    const int s0   = lane * 4;
    const int general = flags[0] | flags[1];
    const size_t base = (size_t)b * TT * MEMS + s0;

    if (!general) {
        // ------------------------ FAST PATH (packed) ------------------------
        f32x2 wr2[2], A2[2], B2[2], nB2[2], vr[2], vi[2], qr[2], qi[2];
        {
            const float4 w4 = *(const float4*)&consts[0 * MEMS + s0];
            const float4 a4 = *(const float4*)&consts[2 * MEMS + s0];
            const float4 b4 = *(const float4*)&consts[3 * MEMS + s0];
            const float4 r4 = *(const float4*)&consts[4 * MEMS + s0];
            const float4 i4 = *(const float4*)&consts[5 * MEMS + s0];
            wr2[0] = {w4.x, w4.y};  wr2[1] = {w4.z, w4.w};
            A2[0]  = {a4.x, a4.y};  A2[1]  = {a4.z, a4.w};
            B2[0]  = {b4.x, b4.y};  B2[1]  = {b4.z, b4.w};
            nB2[0] = {-b4.x, -b4.y}; nB2[1] = {-b4.z, -b4.w};
            vr[0]  = {r4.x, r4.y};  vr[1]  = {r4.z, r4.w};
            vi[0]  = {i4.x, i4.y};  vi[1]  = {i4.z, i4.w};
            qr[0] = vr[0]; qr[1] = vr[1];
            qi[0] = vi[0]; qi[1] = vi[1];
        }
        float4 mbuf[16];
#pragma unroll
        for (int j = 0; j < 16; ++j)
            mbuf[j] = *(const float4*)&M[base + (size_t)j * MEMS];
        for (int t0 = 0; t0 < TT; t0 += 16) {
#pragma unroll
            for (int j = 0; j < 16; ++j) {
                const int t = t0 + j;
                const float4 mc = mbuf[j];
                mbuf[j] = *(const float4*)&M[base + (size_t)(t + 16) * MEMS];
                const f32x2 m0 = {mc.x, mc.y};
                const f32x2 m1 = {mc.z, mc.w};
                // u1 = A o v - B o v_i + wr o q + m   (6 pk ops per slot-pair)
                const f32x2 u1r0 = PKFMA(A2[0], vr[0], PKFMA(nB2[0], vi[0], PKFMA(wr2[0], qr[0], m0)));
                const f32x2 u1i0 = PKFMA(B2[0], vr[0], PKFMA(A2[0], vi[0], wr2[0] * qi[0]));
                const f32x2 u1r1 = PKFMA(A2[1], vr[1], PKFMA(nB2[1], vi[1], PKFMA(wr2[1], qr[1], m1)));
                const f32x2 u1i1 = PKFMA(B2[1], vr[1], PKFMA(A2[1], vi[1], wr2[1] * qi[1]));
                // ||u1||^2 partials
                const f32x2 ps0 = PKFMA(u1i0, u1i0, u1r0 * u1r0);
                const f32x2 ps1 = PKFMA(u1i1, u1i1, u1r1 * u1r1);
                const f32x2 pp  = ps0 + ps1;
                float ss = pp.x + pp.y;
                ss = wave_sum_bcast(ss);
                const float invn = __builtin_amdgcn_rsqf(fmaxf(ss, 1e-16f));
                const f32x2 inv2 = {invn, invn};
                const f32x2 nvr0 = u1r0 * inv2, nvi0 = u1i0 * inv2;
                const f32x2 nvr1 = u1r1 * inv2, nvi1 = u1i1 * inv2;
                const float4 wq = {nvr0.x, nvr0.y, nvr1.x, nvr1.y};
                *(float4*)&Wout[base + (size_t)t * MEMS] = wq;
                qr[0] = vr[0]; qi[0] = vi[0];
                qr[1] = vr[1]; qi[1] = vi[1];
                vr[0] = nvr0;  vi[0] = nvi0;
                vr[1] = nvr1;  vi[1] = nvi1;
            }
        }
        return;
    }

    // ------------------------ GENERAL PATH ------------------------
    float wr4[4], ur[4], ui[4], pr[4], pi[4];
    float rc4[4], rs4[4], ed4[4], pd4[4];
#pragma unroll
    for (int i = 0; i < 4; ++i) {
        wr4[i] = consts[0 * MEMS + s0 + i];
        ur[i]  = consts[4 * MEMS + s0 + i];
        ui[i]  = consts[5 * MEMS + s0 + i];
        pr[i] = ur[i]; pi[i] = ui[i];
        rc4[i] = consts[6 * MEMS + s0 + i];
        rs4[i] = consts[7 * MEMS + s0 + i];
        ed4[i] = eps_diag[s0 + i];
        pd4[i] = pred_diag[s0 + i];
    }
    const float eta  = consts[8 * MEMS];
    const int es_any = flags[0];
    const int ps_any = flags[1];
    float4 mbuf[4];
#pragma unroll
    for (int j = 0; j < 4; ++j)
        mbuf[j] = *(const float4*)&M[base + (size_t)j * MEMS];
    for (int t0 = 0; t0 < TT; t0 += 4) {
#pragma unroll
        for (int j = 0; j < 4; ++j) {
            const int t = t0 + j;
            const float4 mc = mbuf[j];
            mbuf[j] = *(const float4*)&M[base + (size_t)(t + 4) * MEMS];
            float rr[4], ri[4], nr[4], ni[4];
#pragma unroll
            for (int i = 0; i < 4; ++i) {
                rr[i] = ur[i] * rc4[i] - ui[i] * rs4[i];
                ri[i] = ur[i] * rs4[i] + ui[i] * rc4[i];
            }
            const float mv[4] = {mc.x, mc.y, mc.z, mc.w};
#pragma unroll
            for (int i = 0; i < 4; ++i) {
                nr[i] = GAMMA * rr[i] + wr4[i] * pr[i] + eta * ed4[i] * rr[i]
                        - PTS * pd4[i] * ri[i] + mv[i];   // mv already BETA*inj
                ni[i] = GAMMA * ri[i] + wr4[i] * pi[i] + eta * ed4[i] * ri[i]
                        + PTS * pd4[i] * rr[i];
            }
            if (es_any) {
#pragma unroll
                for (int k = 0; k < RANKC; ++k) {
                    float u[4], prj = 0.0f, pij = 0.0f;
#pragma unroll
                    for (int i = 0; i < 4; ++i) {
                        u[i] = eps_fac[(size_t)(s0 + i) * RANKC + k];
                        prj = fmaf(u[i], rr[i], prj);
                        pij = fmaf(u[i], ri[i], pij);
                    }
                    prj = wave_sum_bcast(prj);
                    pij = wave_sum_bcast(pij);
                    const float sc = eta * eps_scale[k];
#pragma unroll
                    for (int i = 0; i < 4; ++i) {
                        nr[i] = fmaf(sc * u[i], prj, nr[i]);
                        ni[i] = fmaf(sc * u[i], pij, ni[i]);
                    }
                }
            }
            if (ps_any) {
#pragma unroll
                for (int k = 0; k < RANKC; ++k) {
                    float u[4], qrj = 0.0f, qij = 0.0f;
#pragma unroll
                    for (int i = 0; i < 4; ++i) {
                        u[i] = pred_fac[(size_t)(s0 + i) * RANKC + k];
                        qrj = fmaf(u[i], rr[i], qrj);
                        qij = fmaf(u[i], ri[i], qij);
                    }
                    qrj = wave_sum_bcast(qrj);
                    qij = wave_sum_bcast(qij);
                    const float sc = PTS * pred_scale[k];
#pragma unroll
                    for (int i = 0; i < 4; ++i) {
                        nr[i] = fmaf(-sc * u[i], qij, nr[i]);
                        ni[i] = fmaf( sc * u[i], qrj, ni[i]);
                    }
                }
            }
            float ss = 0.0f;
#pragma unroll
            for (int i = 0; i < 4; ++i) ss = fmaf(nr[i], nr[i], fmaf(ni[i], ni[i], ss));
            ss = wave_sum_bcast(ss);
            const float inv = __builtin_amdgcn_rsqf(fmaxf(ss, 1e-16f));
#pragma unroll
            for (int i = 0; i < 4; ++i) {
                pr[i] = ur[i]; pi[i] = ui[i];
                ur[i] = nr[i] * inv; ui[i] = ni[i] * inv;
            }
            const float4 wq = {ur[0], ur[1], ur[2], ur[3]};
            *(float4*)&Wout[base + (size_t)t * MEMS] = wq;
        }
    }
}

// ---------------------------------------------------------------------------
// outp: Y = X + W * (alpha * bg[k] * basisT).  W rows are already normalized
// (scan stores v.real), so only the uniform alpha and per-col bg remain; both
// fold into the B-tile load.
// ---------------------------------------------------------------------------
__global__ __launch_bounds__(256) void outp_kernel(const float* __restrict__ W,
                                                   const float* __restrict__ basis,
                                                   const float* __restrict__ x,
                                                   const float* __restrict__ alpha_p,
                                                   const float* __restrict__ consts,
                                                   float* __restrict__ y)
{
    __shared__ float As[32][68];  // [k][m]
    __shared__ float Bs[32][68];  // [k][n]
    const int tid  = threadIdx.x;
    const int row0 = blockIdx.x * 64;
    const int col0 = blockIdx.y * 64;  // h
    const int mt = tid >> 4, nt = tid & 15;
    const float alpha = alpha_p[0];
    const float* bgc  = consts + MEMS;
    const int m0 = tid >> 3, m1 = (tid + 256) >> 3;
    const int kq0 = tid & 7;
    float acc[4][4] = {};
    for (int k0 = 0; k0 < MEMS; k0 += 32) {
        {
            const float4 bgv = *(const float4*)&bgc[k0 + kq0 * 4];
            const float bx = alpha * bgv.x, by = alpha * bgv.y;
            const float bz = alpha * bgv.z, bw = alpha * bgv.w;
            float4 a = *(const float4*)&W[(size_t)(row0 + m0) * MEMS + k0 + kq0 * 4];
            As[kq0 * 4 + 0][m0] = a.x; As[kq0 * 4 + 1][m0] = a.y;
            As[kq0 * 4 + 2][m0] = a.z; As[kq0 * 4 + 3][m0] = a.w;
            float4 b = *(const float4*)&W[(size_t)(row0 + m1) * MEMS + k0 + kq0 * 4];
            As[kq0 * 4 + 0][m1] = b.x; As[kq0 * 4 + 1][m1] = b.y;
            As[kq0 * 4 + 2][m1] = b.z; As[kq0 * 4 + 3][m1] = b.w;
            int q = tid; int n = q >> 3;
            float4 c = *(const float4*)&basis[(size_t)(col0 + n) * SLOTS + k0 + kq0 * 4];
            Bs[kq0 * 4 + 0][n] = c.x * bx; Bs[kq0 * 4 + 1][n] = c.y * by;
            Bs[kq0 * 4 + 2][n] = c.z * bz; Bs[kq0 * 4 + 3][n] = c.w * bw;
            q = tid + 256; n = q >> 3;
            float4 d = *(const float4*)&basis[(size_t)(col0 + n) * SLOTS + k0 + kq0 * 4];
            Bs[kq0 * 4 + 0][n] = d.x * bx; Bs[kq0 * 4 + 1][n] = d.y * by;
            Bs[kq0 * 4 + 2][n] = d.z * bz; Bs[kq0 * 4 + 3][n] = d.w * bw;
        }
        __syncthreads();
#pragma unroll
        for (int kk = 0; kk < 32; ++kk) {
            float4 a = *(const float4*)&As[kk][mt * 4];
            float4 b = *(const float4*)&Bs[kk][nt * 4];
            float av[4] = {a.x, a.y, a.z, a.w};
            float bv[4] = {b.x, b.y, b.z, b.w};
#pragma unroll
            for (int i = 0; i < 4; ++i)
#pragma unroll
                for (int j = 0; j < 4; ++j) acc[i][j] += av[i] * bv[j];
        }
        __syncthreads();
    }
#pragma unroll
    for (int i = 0; i < 4; ++i) {
        const size_t ro = (size_t)(row0 + mt * 4 + i) * HD + col0 + nt * 4;
        float4 xv = *(const float4*)&x[ro];
        float4 o  = {xv.x + acc[i][0], xv.y + acc[i][1],
                     xv.z + acc[i][2], xv.w + acc[i][3]};
        *(float4*)&y[ro] = o;
    }
}

// ---------------------------------------------------------------------------
extern "C" void kernel_launch(void* const* d_in, const int* in_sizes, int n_in,
                              void* d_out, int out_size, void* d_ws, size_t ws_size,
                              hipStream_t stream)
{
    const float* x          = (const float*)d_in[0];
    const float* basis      = (const float*)d_in[1];
    const float* t0re       = (const float*)d_in[2];
    const float* t0im       = (const float*)d_in[3];
    const float* eta_raw    = (const float*)d_in[4];
    const float* alpha      = (const float*)d_in[5];
    const float* trot       = (const float*)d_in[6];
    const float* w_r        = (const float*)d_in[7];
    const float* bgate      = (const float*)d_in[8];
    const float* eps_fac    = (const float*)d_in[9];
    const float* eps_scale  = (const float*)d_in[10];
    const float* eps_diag   = (const float*)d_in[11];
    const float* pred_fac   = (const float*)d_in[12];
    const float* pred_scale = (const float*)d_in[13];
    const float* pred_diag  = (const float*)d_in[14];
    float* out = (float*)d_out;

    const size_t szM = (size_t)RR * MEMS * sizeof(float);  // 32 MB
    const size_t szW = szM;                                 // 32 MB
    const size_t szC = 16384;                               // consts + flags

    char* ws = (char*)d_ws;
    float *Mbuf, *Wbuf, *cbuf;
    if (ws_size >= szM + szW + szC) {
        Mbuf = (float*)(ws);
        Wbuf = (float*)(ws + szM);
        cbuf = (float*)(ws + szM + szW);
    } else {
        // fallback: stage M in d_out (consumed by topk+scan before outp rewrites it)
        Mbuf = (float*)d_out;
        Wbuf = (float*)(ws);
        cbuf = (float*)(ws + szW);
    }
    int* fbuf = (int*)(cbuf + 8 * MEMS + 16);

    prep_kernel<<<1, 256, 0, stream>>>(t0re, t0im, eta_raw, trot, w_r, bgate,
                                       eps_scale, pred_scale, eps_diag, pred_diag,
                                       cbuf, fbuf);
    proj_kernel<<<dim3(RR / 64, MEMS / 64), 256, 0, stream>>>(x, basis, Mbuf);
    topk_kernel<<<RR, 64, 0, stream>>>(Mbuf);
    scan_kernel<<<BATCH, 64, 0, stream>>>(Mbuf, cbuf, fbuf,
                                          eps_fac, eps_scale, eps_diag,
                                          pred_fac, pred_scale, pred_diag,
                                          Wbuf);
    outp_kernel<<<dim3(RR / 64, HD / 64), 256, 0, stream>>>(Wbuf, basis, x, alpha,
                                                            cbuf, out);
}

// Round 2
// 1068.622 us; speedup vs baseline: 1.2101x; 1.0347x over previous
//
#include <hip/hip_runtime.h>
#include <cstdint>
#include <cstddef>

#define HD    1024
#define SLOTS 272
#define MEMS  256
#define BATCH 8
#define TT    4096
#define RR    (BATCH*TT)
#define RANKC 10

#define GAMMA 0.92f
#define BETA  0.08f
#define PTS   0.4f

// packed fp32 (v_pk_fma_f32 / v_pk_mul_f32 on gfx950): halves VALU issue count
// in the single-wave scan.
typedef float f32x2 __attribute__((ext_vector_type(2)));
#define PKFMA(a, b, c) __builtin_elementwise_fma((a), (b), (c))

// ---------------------------------------------------------------------------
// DPP wave64 sum-allreduce: 6 VALU-speed cross-lane adds + readlane broadcast.
// ---------------------------------------------------------------------------
#define DPP_ADD(v, ctrl, rmask)                                                   \
    v += __int_as_float(__builtin_amdgcn_update_dpp(                              \
        0, __float_as_int(v), (ctrl), (rmask), 0xf, true))

__device__ __forceinline__ float wave_sum_bcast(float v)
{
    DPP_ADD(v, 0xB1,  0xf);   // quad_perm [1,0,3,2]  : + lane^1
    DPP_ADD(v, 0x4E,  0xf);   // quad_perm [2,3,0,1]  : + lane^2
    DPP_ADD(v, 0x141, 0xf);   // row_half_mirror      : + other quad
    DPP_ADD(v, 0x140, 0xf);   // row_mirror           : + other 8-group
    DPP_ADD(v, 0x142, 0xa);   // row_bcast15 -> rows 1,3
    DPP_ADD(v, 0x143, 0xc);   // row_bcast31 -> rows 2,3 (lane 63 = total)
    return __int_as_float(__builtin_amdgcn_readlane(__float_as_int(v), 63));
}

// ---------------------------------------------------------------------------
// prep: per-slot constants.
// consts (floats): [0]=wr[256] [256]=bg[256] [512]=A[256] [768]=B[256]
// [1024]=v0re[256] [1280]=v0im[256] [1536]=cos[256] [1792]=sin[256] [2048]=eta
//   c1 = gamma + eta*eps_diag, c2 = PTS*pred_diag, A = c1*cos - c2*sin,
//   B = c1*sin + c2*cos.  flags: [0]=eps_scale any nz, [1]=pred_scale any nz.
// ---------------------------------------------------------------------------
__global__ void prep_kernel(const float* __restrict__ t0re, const float* __restrict__ t0im,
                            const float* __restrict__ eta_raw,
                            const float* __restrict__ trot, const float* __restrict__ w_r,
                            const float* __restrict__ bgate,
                            const float* __restrict__ eps_scale, const float* __restrict__ pred_scale,
                            const float* __restrict__ eps_diag, const float* __restrict__ pred_diag,
                            float* __restrict__ consts, int* __restrict__ flags)
{
    __shared__ float red[MEMS];
    const int s = threadIdx.x;  // 256 threads
    const float tr = t0re[s], ti = t0im[s];
    red[s] = tr * tr + ti * ti;
    __syncthreads();
    for (int off = 128; off > 0; off >>= 1) {
        if (s < off) red[s] += red[s + off];
        __syncthreads();
    }
    const float nrm = sqrtf(fmaxf(red[0], 1e-16f));
    const float eta = log1pf(expf(eta_raw[0]));
    const float rc = cosf(trot[s]), rs = sinf(trot[s]);
    const float c1 = GAMMA + eta * eps_diag[s];
    const float c2 = PTS * pred_diag[s];
    consts[0 * MEMS + s] = 1.0f / (1.0f + expf(-w_r[s]));
    consts[1 * MEMS + s] = 1.0f / (1.0f + expf(-bgate[s]));
    consts[2 * MEMS + s] = c1 * rc - c2 * rs;   // A
    consts[3 * MEMS + s] = c1 * rs + c2 * rc;   // B
    consts[4 * MEMS + s] = tr / nrm;
    consts[5 * MEMS + s] = ti / nrm;
    consts[6 * MEMS + s] = rc;
    consts[7 * MEMS + s] = rs;
    if (s == 0) {
        consts[8 * MEMS] = eta;
        int f1 = 0, f2 = 0;
        for (int k = 0; k < RANKC; ++k) {
            if (eps_scale[k]  != 0.0f) f1 = 1;
            if (pred_scale[k] != 0.0f) f2 = 1;
        }
        flags[0] = f1;
        flags[1] = f2;
    }
}

// ---------------------------------------------------------------------------
// proj: M(R x 256) = X(R x 1024) * Q,  Q[k][n] = basis[k*272 + n]
// ---------------------------------------------------------------------------
__global__ __launch_bounds__(256) void proj_kernel(const float* __restrict__ x,
                                                   const float* __restrict__ basis,
                                                   float* __restrict__ M)
{
    __shared__ float As[32][68];  // [k][m], padded
    __shared__ float Bs[32][68];  // [k][n], padded
    const int tid  = threadIdx.x;
    const int row0 = blockIdx.x * 64;
    const int col0 = blockIdx.y * 64;
    const int mt = tid >> 4, nt = tid & 15;
    float acc[4][4] = {};
    for (int k0 = 0; k0 < HD; k0 += 32) {
        {
            int q = tid, m = q >> 3, kq = q & 7;
            float4 a = *(const float4*)&x[(size_t)(row0 + m) * HD + k0 + kq * 4];
            As[kq * 4 + 0][m] = a.x; As[kq * 4 + 1][m] = a.y;
            As[kq * 4 + 2][m] = a.z; As[kq * 4 + 3][m] = a.w;
            q = tid + 256; m = q >> 3; kq = q & 7;
            float4 b = *(const float4*)&x[(size_t)(row0 + m) * HD + k0 + kq * 4];
            As[kq * 4 + 0][m] = b.x; As[kq * 4 + 1][m] = b.y;
            As[kq * 4 + 2][m] = b.z; As[kq * 4 + 3][m] = b.w;
            q = tid; int k = q >> 4; int nq = q & 15;
            float4 c = *(const float4*)&basis[(size_t)(k0 + k) * SLOTS + col0 + nq * 4];
            *(float4*)&Bs[k][nq * 4] = c;
            q = tid + 256; k = q >> 4; nq = q & 15;
            float4 d = *(const float4*)&basis[(size_t)(k0 + k) * SLOTS + col0 + nq * 4];
            *(float4*)&Bs[k][nq * 4] = d;
        }
        __syncthreads();
#pragma unroll
        for (int kk = 0; kk < 32; ++kk) {
            float4 a = *(const float4*)&As[kk][mt * 4];
            float4 b = *(const float4*)&Bs[kk][nt * 4];
            float av[4] = {a.x, a.y, a.z, a.w};
            float bv[4] = {b.x, b.y, b.z, b.w};
#pragma unroll
            for (int i = 0; i < 4; ++i)
#pragma unroll
                for (int j = 0; j < 4; ++j) acc[i][j] += av[i] * bv[j];
        }
        __syncthreads();
    }
#pragma unroll
    for (int i = 0; i < 4; ++i) {
        float4 o = {acc[i][0], acc[i][1], acc[i][2], acc[i][3]};
        *(float4*)&M[(size_t)(row0 + mt * 4 + i) * MEMS + col0 + nt * 4] = o;
    }
}

// ---------------------------------------------------------------------------
// topk: per (b,t) row, find 8th-largest |m| (dup-counting), then mask the row
// IN PLACE: M[r,s] <- (|m|>=kth) ? BETA*m : 0.  Scan consumes it directly.
// ---------------------------------------------------------------------------
__global__ __launch_bounds__(64) void topk_kernel(float* __restrict__ M)
{
    const int r    = blockIdx.x;
    const int lane = threadIdx.x;
    float4 v = *(const float4*)&M[(size_t)r * MEMS + lane * 4];
    float vals[4] = {fabsf(v.x), fabsf(v.y), fabsf(v.z), fabsf(v.w)};
    float keep[4] = {vals[0], vals[1], vals[2], vals[3]};
    float kv = 0.0f;
#pragma unroll
    for (int it = 0; it < 8; ++it) {
        float lm = vals[0]; int li = 0;
#pragma unroll
        for (int j = 1; j < 4; ++j)
            if (vals[j] > lm) { lm = vals[j]; li = j; }
        float bm = lm; int bi = lane * 4 + li;
#pragma unroll
        for (int off = 1; off < 64; off <<= 1) {
            float om = __shfl_xor(bm, off);
            int   oi = __shfl_xor(bi, off);
            if (om > bm || (om == bm && oi < bi)) { bm = om; bi = oi; }
        }
        kv = bm;
        if ((bi >> 2) == lane) vals[bi & 3] = -1.0f;
    }
    float4 o;
    o.x = (keep[0] >= kv) ? BETA * v.x : 0.0f;
    o.y = (keep[1] >= kv) ? BETA * v.y : 0.0f;
    o.z = (keep[2] >= kv) ? BETA * v.z : 0.0f;
    o.w = (keep[3] >= kv) ? BETA * v.w : 0.0f;
    *(float4*)&M[(size_t)r * MEMS + lane * 4] = o;
}

// ---------------------------------------------------------------------------
// scan: one wave per batch, 4 slots/lane, all state in registers.
// M is pre-masked (= BETA*inj).
// DEFERRED NORMALIZATION: carry the RAW state w_{t-1}, its per-lane norm
// partial ssp, and the normalized prev-prev q = s_{t-2}.  Per step:
//   ic = rsqrt(reduce(ssp))              (6-dep DPP tree -- the latency hog)
//   L  = Ahat o w   (raw; by linearity ic*L(w) = L(s_{t-1}))   } independent,
//   wq = wr o q + m (q ready a full step early)                } overlap tree
//   w' = ic*L + wq            (only this join waits on rsq)
//   q' = w*ic = s_{t-1}       (off-chain; IS the row to store)
// Store row t-1 each step (row 0 double-written), epilogue stores row TT-1.
// This takes the 6-stage cross-lane reduce + rsq tail off the serial chain;
// round-1 measured 246 cyc/step fully serialized.
// Depth-16 prefetch ring; prefetch may read <=16 rows past the slice (valid
// adjacent ws/d_out memory, values unused).
// ---------------------------------------------------------------------------
__global__ __launch_bounds__(64) void scan_kernel(const float* __restrict__ M,
                                                  const float* __restrict__ consts,
                                                  const int* __restrict__ flags,
                                                  const float* __restrict__ eps_fac,
                                                  const float* __restrict__ eps_scale,
                                                  const float* __restrict__ eps_diag,
                                                  const float* __restrict__ pred_fac,
                                                  const float* __restrict__ pred_scale,
                                                  const float* __restrict__ pred_diag,
                                                  float* __restrict__ Wout)
{
    const int b    = blockIdx.x;
    const int lane = threadIdx.x;
    const int s0   = lane * 4;
    const int general = flags[0] | flags[1];
    const size_t base = (size_t)b * TT * MEMS + s0;

    if (!general) {
        // ------------------------ FAST PATH (deferred norm) ------------------------
        f32x2 wrg[2], A2[2], B2[2], nB2[2];
        f32x2 wre[2], wim[2], qre[2], qim[2];
        {
            const float4 w4 = *(const float4*)&consts[0 * MEMS + s0];
            const float4 a4 = *(const float4*)&consts[2 * MEMS + s0];
            const float4 b4 = *(const float4*)&consts[3 * MEMS + s0];
            const float4 r4 = *(const float4*)&consts[4 * MEMS + s0];
            const float4 i4 = *(const float4*)&consts[5 * MEMS + s0];
            wrg[0] = {w4.x, w4.y};  wrg[1] = {w4.z, w4.w};
            A2[0]  = {a4.x, a4.y};  A2[1]  = {a4.z, a4.w};
            B2[0]  = {b4.x, b4.y};  B2[1]  = {b4.z, b4.w};
            nB2[0] = {-b4.x, -b4.y}; nB2[1] = {-b4.z, -b4.w};
            wre[0] = {r4.x, r4.y};  wre[1] = {r4.z, r4.w};
            wim[0] = {i4.x, i4.y};  wim[1] = {i4.z, i4.w};
            qre[0] = wre[0]; qre[1] = wre[1];   // prev = tape0 (normalized)
            qim[0] = wim[0]; qim[1] = wim[1];
        }
        float ssp;  // per-lane partial of ||w||^2 (sums to 1 for the init state)
        {
            const f32x2 p0 = PKFMA(wim[0], wim[0], wre[0] * wre[0]);
            const f32x2 p1 = PKFMA(wim[1], wim[1], wre[1] * wre[1]);
            const f32x2 pp = p0 + p1;
            ssp = pp.x + pp.y;
        }
        float4 mbuf[16];
#pragma unroll
        for (int j = 0; j < 16; ++j)
            mbuf[j] = *(const float4*)&M[base + (size_t)j * MEMS];
        for (int t0 = 0; t0 < TT; t0 += 16) {
#pragma unroll
            for (int j = 0; j < 16; ++j) {
                const int t = t0 + j;
                const float4 mc = mbuf[j];
                mbuf[j] = *(const float4*)&M[base + (size_t)(t + 16) * MEMS];
                // reduce ||w_{t-1}||^2 -> ic  (overlaps with L / wq below)
                const float stot = wave_sum_bcast(ssp);
                const float icv  = __builtin_amdgcn_rsqf(fmaxf(stot, 1e-16f));
                const f32x2 ic2  = {icv, icv};
                // L = Ahat o w   (raw prev state; independent of reduction)
                const f32x2 Lr0 = PKFMA(A2[0], wre[0], nB2[0] * wim[0]);
                const f32x2 Li0 = PKFMA(B2[0], wre[0], A2[0]  * wim[0]);
                const f32x2 Lr1 = PKFMA(A2[1], wre[1], nB2[1] * wim[1]);
                const f32x2 Li1 = PKFMA(B2[1], wre[1], A2[1]  * wim[1]);
                // wq = wr o q + m   (q normalized, ready a step early; m real)
                const f32x2 m0 = {mc.x, mc.y};
                const f32x2 m1 = {mc.z, mc.w};
                const f32x2 wqr0 = PKFMA(wrg[0], qre[0], m0);
                const f32x2 wqi0 = wrg[0] * qim[0];
                const f32x2 wqr1 = PKFMA(wrg[1], qre[1], m1);
                const f32x2 wqi1 = wrg[1] * qim[1];
                // new raw state  (single FMA joins the reduction result)
                const f32x2 u1r0 = PKFMA(ic2, Lr0, wqr0);
                const f32x2 u1i0 = PKFMA(ic2, Li0, wqi0);
                const f32x2 u1r1 = PKFMA(ic2, Lr1, wqr1);
                const f32x2 u1i1 = PKFMA(ic2, Li1, wqi1);
                // next per-lane norm partial
                const f32x2 ps0 = PKFMA(u1i0, u1i0, u1r0 * u1r0);
                const f32x2 ps1 = PKFMA(u1i1, u1i1, u1r1 * u1r1);
                const f32x2 pp  = ps0 + ps1;
                // s_{t-1} = w * ic : next q AND the row to store (off-chain)
                const f32x2 nr0 = wre[0] * ic2, ni0 = wim[0] * ic2;
                const f32x2 nr1 = wre[1] * ic2, ni1 = wim[1] * ic2;
                const int tr = (t - 1) < 0 ? 0 : (t - 1);  // uniform SALU
                const float4 wq4 = {nr0.x, nr0.y, nr1.x, nr1.y};
                *(float4*)&Wout[base + (size_t)tr * MEMS] = wq4;
                // rotate carries
                qre[0] = nr0;  qim[0] = ni0;  qre[1] = nr1;  qim[1] = ni1;
                wre[0] = u1r0; wim[0] = u1i0; wre[1] = u1r1; wim[1] = u1i1;
                ssp = pp.x + pp.y;
            }
        }
        // epilogue: final row TT-1 = normalized w_{TT-1}
        {
            const float stot = wave_sum_bcast(ssp);
            const float icv  = __builtin_amdgcn_rsqf(fmaxf(stot, 1e-16f));
            const float4 wq4 = {wre[0].x * icv, wre[0].y * icv,
                                wre[1].x * icv, wre[1].y * icv};
            *(float4*)&Wout[base + (size_t)(TT - 1) * MEMS] = wq4;
        }
        return;
    }

    // ------------------------ GENERAL PATH ------------------------
    float wr4[4], ur[4], ui[4], pr[4], pi[4];
    float rc4[4], rs4[4], ed4[4], pd4[4];
#pragma unroll
    for (int i = 0; i < 4; ++i) {
        wr4[i] = consts[0 * MEMS + s0 + i];
        ur[i]  = consts[4 * MEMS + s0 + i];
        ui[i]  = consts[5 * MEMS + s0 + i];
        pr[i] = ur[i]; pi[i] = ui[i];
        rc4[i] = consts[6 * MEMS + s0 + i];
        rs4[i] = consts[7 * MEMS + s0 + i];
        ed4[i] = eps_diag[s0 + i];
        pd4[i] = pred_diag[s0 + i];
    }
    const float eta  = consts[8 * MEMS];
    const int es_any = flags[0];
    const int ps_any = flags[1];
    float4 mbuf[4];
#pragma unroll
    for (int j = 0; j < 4; ++j)
        mbuf[j] = *(const float4*)&M[base + (size_t)j * MEMS];
    for (int t0 = 0; t0 < TT; t0 += 4) {
#pragma unroll
        for (int j = 0; j < 4; ++j) {
            const int t = t0 + j;
            const float4 mc = mbuf[j];
            mbuf[j] = *(const float4*)&M[base + (size_t)(t + 4) * MEMS];
            float rr[4], ri[4], nr[4], ni[4];
#pragma unroll
            for (int i = 0; i < 4; ++i) {
                rr[i] = ur[i] * rc4[i] - ui[i] * rs4[i];
                ri[i] = ur[i] * rs4[i] + ui[i] * rc4[i];
            }
            const float mv[4] = {mc.x, mc.y, mc.z, mc.w};
#pragma unroll
            for (int i = 0; i < 4; ++i) {
                nr[i] = GAMMA * rr[i] + wr4[i] * pr[i] + eta * ed4[i] * rr[i]
                        - PTS * pd4[i] * ri[i] + mv[i];   // mv already BETA*inj
                ni[i] = GAMMA * ri[i] + wr4[i] * pi[i] + eta * ed4[i] * ri[i]
                        + PTS * pd4[i] * rr[i];
            }
            if (es_any) {
#pragma unroll
                for (int k = 0; k < RANKC; ++k) {
                    float u[4], prj = 0.0f, pij = 0.0f;
#pragma unroll
                    for (int i = 0; i < 4; ++i) {
                        u[i] = eps_fac[(size_t)(s0 + i) * RANKC + k];
                        prj = fmaf(u[i], rr[i], prj);
                        pij = fmaf(u[i], ri[i], pij);
                    }
                    prj = wave_sum_bcast(prj);
                    pij = wave_sum_bcast(pij);
                    const float sc = eta * eps_scale[k];
#pragma unroll
                    for (int i = 0; i < 4; ++i) {
                        nr[i] = fmaf(sc * u[i], prj, nr[i]);
                        ni[i] = fmaf(sc * u[i], pij, ni[i]);
                    }
                }
            }
            if (ps_any) {
#pragma unroll
                for (int k = 0; k < RANKC; ++k) {
                    float u[4], qrj = 0.0f, qij = 0.0f;
#pragma unroll
                    for (int i = 0; i < 4; ++i) {
                        u[i] = pred_fac[(size_t)(s0 + i) * RANKC + k];
                        qrj = fmaf(u[i], rr[i], qrj);
                        qij = fmaf(u[i], ri[i], qij);
                    }
                    qrj = wave_sum_bcast(qrj);
                    qij = wave_sum_bcast(qij);
                    const float sc = PTS * pred_scale[k];
#pragma unroll
                    for (int i = 0; i < 4; ++i) {
                        nr[i] = fmaf(-sc * u[i], qij, nr[i]);
                        ni[i] = fmaf( sc * u[i], qrj, ni[i]);
                    }
                }
            }
            float ss = 0.0f;
#pragma unroll
            for (int i = 0; i < 4; ++i) ss = fmaf(nr[i], nr[i], fmaf(ni[i], ni[i], ss));
            ss = wave_sum_bcast(ss);
            const float inv = __builtin_amdgcn_rsqf(fmaxf(ss, 1e-16f));
#pragma unroll
            for (int i = 0; i < 4; ++i) {
                pr[i] = ur[i]; pi[i] = ui[i];
                ur[i] = nr[i] * inv; ui[i] = ni[i] * inv;
            }
            const float4 wq = {ur[0], ur[1], ur[2], ur[3]};
            *(float4*)&Wout[base + (size_t)t * MEMS] = wq;
        }
    }
}

// ---------------------------------------------------------------------------
// outp: Y = X + W * (alpha * bg[k] * basisT).  W rows are already normalized
// (scan stores s.real), so only the uniform alpha and per-col bg remain; both
// fold into the B-tile load.
// ---------------------------------------------------------------------------
__global__ __launch_bounds__(256) void outp_kernel(const float* __restrict__ W,
                                                   const float* __restrict__ basis,
                                                   const float* __restrict__ x,
                                                   const float* __restrict__ alpha_p,
                                                   const float* __restrict__ consts,
                                                   float* __restrict__ y)
{
    __shared__ float As[32][68];  // [k][m]
    __shared__ float Bs[32][68];  // [k][n]
    const int tid  = threadIdx.x;
    const int row0 = blockIdx.x * 64;
    const int col0 = blockIdx.y * 64;  // h
    const int mt = tid >> 4, nt = tid & 15;
    const float alpha = alpha_p[0];
    const float* bgc  = consts + MEMS;
    const int m0 = tid >> 3, m1 = (tid + 256) >> 3;
    const int kq0 = tid & 7;
    float acc[4][4] = {};
    for (int k0 = 0; k0 < MEMS; k0 += 32) {
        {
            const float4 bgv = *(const float4*)&bgc[k0 + kq0 * 4];
            const float bx = alpha * bgv.x, by = alpha * bgv.y;
            const float bz = alpha * bgv.z, bw = alpha * bgv.w;
            float4 a = *(const float4*)&W[(size_t)(row0 + m0) * MEMS + k0 + kq0 * 4];
            As[kq0 * 4 + 0][m0] = a.x; As[kq0 * 4 + 1][m0] = a.y;
            As[kq0 * 4 + 2][m0] = a.z; As[kq0 * 4 + 3][m0] = a.w;
            float4 b = *(const float4*)&W[(size_t)(row0 + m1) * MEMS + k0 + kq0 * 4];
            As[kq0 * 4 + 0][m1] = b.x; As[kq0 * 4 + 1][m1] = b.y;
            As[kq0 * 4 + 2][m1] = b.z; As[kq0 * 4 + 3][m1] = b.w;
            int q = tid; int n = q >> 3;
            float4 c = *(const float4*)&basis[(size_t)(col0 + n) * SLOTS + k0 + kq0 * 4];
            Bs[kq0 * 4 + 0][n] = c.x * bx; Bs[kq0 * 4 + 1][n] = c.y * by;
            Bs[kq0 * 4 + 2][n] = c.z * bz; Bs[kq0 * 4 + 3][n] = c.w * bw;
            q = tid + 256; n = q >> 3;
            float4 d = *(const float4*)&basis[(size_t)(col0 + n) * SLOTS + k0 + kq0 * 4];
            Bs[kq0 * 4 + 0][n] = d.x * bx; Bs[kq0 * 4 + 1][n] = d.y * by;
            Bs[kq0 * 4 + 2][n] = d.z * bz; Bs[kq0 * 4 + 3][n] = d.w * bw;
        }
        __syncthreads();
#pragma unroll
        for (int kk = 0; kk < 32; ++kk) {
            float4 a = *(const float4*)&As[kk][mt * 4];
            float4 b = *(const float4*)&Bs[kk][nt * 4];
            float av[4] = {a.x, a.y, a.z, a.w};
            float bv[4] = {b.x, b.y, b.z, b.w};
#pragma unroll
            for (int i = 0; i < 4; ++i)
#pragma unroll
                for (int j = 0; j < 4; ++j) acc[i][j] += av[i] * bv[j];
        }
        __syncthreads();
    }
#pragma unroll
    for (int i = 0; i < 4; ++i) {
        const size_t ro = (size_t)(row0 + mt * 4 + i) * HD + col0 + nt * 4;
        float4 xv = *(const float4*)&x[ro];
        float4 o  = {xv.x + acc[i][0], xv.y + acc[i][1],
                     xv.z + acc[i][2], xv.w + acc[i][3]};
        *(float4*)&y[ro] = o;
    }
}

// ---------------------------------------------------------------------------
extern "C" void kernel_launch(void* const* d_in, const int* in_sizes, int n_in,
                              void* d_out, int out_size, void* d_ws, size_t ws_size,
                              hipStream_t stream)
{
    const float* x          = (const float*)d_in[0];
    const float* basis      = (const float*)d_in[1];
    const float* t0re       = (const float*)d_in[2];
    const float* t0im       = (const float*)d_in[3];
    const float* eta_raw    = (const float*)d_in[4];
    const float* alpha      = (const float*)d_in[5];
    const float* trot       = (const float*)d_in[6];
    const float* w_r        = (const float*)d_in[7];
    const float* bgate      = (const float*)d_in[8];
    const float* eps_fac    = (const float*)d_in[9];
    const float* eps_scale  = (const float*)d_in[10];
    const float* eps_diag   = (const float*)d_in[11];
    const float* pred_fac   = (const float*)d_in[12];
    const float* pred_scale = (const float*)d_in[13];
    const float* pred_diag  = (const float*)d_in[14];
    float* out = (float*)d_out;

    const size_t szM = (size_t)RR * MEMS * sizeof(float);  // 32 MB
    const size_t szW = szM;                                 // 32 MB
    const size_t szC = 16384;                               // consts + flags

    char* ws = (char*)d_ws;
    float *Mbuf, *Wbuf, *cbuf;
    if (ws_size >= szM + szW + szC) {
        Mbuf = (float*)(ws);
        Wbuf = (float*)(ws + szM);
        cbuf = (float*)(ws + szM + szW);
    } else {
        // fallback: stage M in d_out (consumed by topk+scan before outp rewrites it)
        Mbuf = (float*)d_out;
        Wbuf = (float*)(ws);
        cbuf = (float*)(ws + szW);
    }
    int* fbuf = (int*)(cbuf + 8 * MEMS + 16);

    prep_kernel<<<1, 256, 0, stream>>>(t0re, t0im, eta_raw, trot, w_r, bgate,
                                       eps_scale, pred_scale, eps_diag, pred_diag,
                                       cbuf, fbuf);
    proj_kernel<<<dim3(RR / 64, MEMS / 64), 256, 0, stream>>>(x, basis, Mbuf);
    topk_kernel<<<RR, 64, 0, stream>>>(Mbuf);
    scan_kernel<<<BATCH, 64, 0, stream>>>(Mbuf, cbuf, fbuf,
                                          eps_fac, eps_scale, eps_diag,
                                          pred_fac, pred_scale, pred_diag,
                                          Wbuf);
    outp_kernel<<<dim3(RR / 64, HD / 64), 256, 0, stream>>>(Wbuf, basis, x, alpha,
                                                            cbuf, out);
}